// Round 13
// baseline (661.033 us; speedup 1.0000x reference)
//
#include <hip/hip_runtime.h>
#include <hip/hip_bf16.h>

#define NRBF 60
#define KTRUNC 32          // rbf r>=32 is < 1.4e-13 for d <= sqrt(3) < cutoff

// ws float offsets (unified layout for both paths)
#define WS_X      0          // 512*128
#define WS_T      65536      // 512*128
#define WS_WC     131072     // 4*128*128
#define WS_BC     196608     // 4*128
#define WS_CORR   197120     // 4*128
#define WS_POOL   197632     // 16*128
#define WS_BAR    199680     // 8 barrier counters*32 u32 + done ctr + fail flag (256 u32)
#define WS_BF     199936     // 4 layers * 512 short8 (8192 floats)
#define WS_PART   208128     // 32*512*128 partials (2097152 floats)
#define WS_AF     2305280    // 512*32*64 short8 (4194304 floats) = 16.8 MB
#define WS_TOTALF 6499584    // floats

typedef short short8 __attribute__((ext_vector_type(8)));
typedef float f32x4 __attribute__((ext_vector_type(4)));

__device__ inline float fexp2(float x) { return __builtin_amdgcn_exp2f(x); }
__device__ inline float frcp(float x) { return __builtin_amdgcn_rcpf(x); }
__device__ inline float silu_f(float z) {
  float e = fexp2(z * -1.44269504f);
  return z * frcp(1.0f + e);
}
__device__ inline short f2bf(float f) {
  unsigned u = __float_as_uint(f);
  unsigned r = (u + 0x7FFFu + ((u >> 16) & 1u)) >> 16;
  return (short)r;
}
__device__ inline float bf2f(short b) {
  unsigned u = ((unsigned)(unsigned short)b) << 16;
  return __uint_as_float(u);
}

// ---------------------------------------------------------------------------
// Sharded grid barrier. Counters live in ws, poisoned to 0xAAAAAAAA before
// every attempt -> arrivals = load - 0xAAAAAAAA. 8 shards, 128B apart.
// Plain atomic spin barrier — needs co-residency only. On timeout writes a
// sentinel to bar[252] so the host probe can detect failure.
// R5/R7/R9 evidence: non-residency shows as ~0.15s/barrier timeout storms;
// real barrier waits are ~2K tries, so 1M tries is ~500x margin.
// ---------------------------------------------------------------------------
__device__ inline void grid_barrier(unsigned* bar, int seq) {
  __syncthreads();
  if (threadIdx.x == 0) {
    __threadfence();
    atomicAdd(&bar[(blockIdx.x & 7) * 32], 1u);
  }
  if (threadIdx.x < 8) {
    const unsigned cnt = (gridDim.x - threadIdx.x + 7) >> 3;
    const unsigned tgt = (unsigned)(seq + 1) * cnt;
    unsigned tries = 0;
    while ((__hip_atomic_load(&bar[threadIdx.x * 32], __ATOMIC_RELAXED,
                              __HIP_MEMORY_SCOPE_AGENT) -
            0xAAAAAAAAu) < tgt) {
      if (++tries > 1000000u) {  // fail-visible, never hang
        __hip_atomic_store(&bar[252], 0xDEADBEEFu, __ATOMIC_RELAXED,
                           __HIP_MEMORY_SCOPE_AGENT);
        break;
      }
      __builtin_amdgcn_s_sleep(1);
    }
  }
  __threadfence();
  __syncthreads();
}

// ===========================================================================
// Shared device phase helpers.
// R9 lesson: in the fused kernel, whole-function register allocation across
// all inlined phases drove total regs >256/wave (1 block/CU); forcing
// launch_bounds(256,2) just spilled (+28MB scratch, 3x regression — R7, R9).
// noinline isolates each phase's register peak so the kernel's natural
// footprint ~= max(per-phase), letting 2-3 blocks/CU co-reside WITHOUT
// coercion. Call overhead: ~100cy x thousands of calls = sub-us total.
// ===========================================================================
__device__ __attribute__((noinline)) void setup_vblock(
    int vb, int tid, const int* an, const float* pos,
    const float* emb, const float* msg_w1,
    const float* msg_b1, const float* msg_w2,
    const float* msg_b2, const float* upd_w1,
    const float* centers, const float* widths,
    float* ws, float xl[2][128])
{
  float* x    = ws + WS_X;
  float* t    = ws + WS_T;
  float* Wc   = ws + WS_WC;
  float* bc   = ws + WS_BC;
  float* corr = ws + WS_CORR;
  float* pool = ws + WS_POOL;
  const int lane = tid & 63;
  const int quad = lane >> 4, l16 = lane & 15;

  if (vb < 256) {
    const int jj = tid >> 7, h = tid & 127;
    const int i = vb * 2 + jj;
    int a = an[i]; a = a < 0 ? 0 : (a > 99 ? 99 : a);
    float xv = emb[a * 128 + h];
    x[i * 128 + h] = xv;
    xl[jj][h] = xv;
    __syncthreads();
    float a0 = 0.0f, a1 = 0.0f;
    for (int k = 0; k < 128; k += 2) {
      a0 += xl[jj][k] * msg_w1[k * 128 + h];
      a1 += xl[jj][k + 1] * msg_w1[(k + 1) * 128 + h];
    }
    t[i * 128 + h] = msg_b1[h] + a0 + a1;
    __syncthreads();
  } else if (vb < 768) {
    const int j = vb - 256;
    const int g = tid >> 6;
    const float pjx = pos[j * 3], pjy = pos[j * 3 + 1], pjz = pos[j * 3 + 2];
    float cr[8], k2[8];
#pragma unroll
    for (int u = 0; u < 8; ++u) {
      int r = quad * 8 + u;
      float w = widths[r];
      cr[u] = centers[r];
      k2[u] = -0.7213475204444817f / (w * w);
    }
    short8* AFp = (short8*)(ws + WS_AF);
    for (int iter = 0; iter < 8; ++iter) {
      int ic = iter * 4 + g;
      int i = ic * 16 + l16;
      float dx = pos[i * 3] - pjx, dy = pos[i * 3 + 1] - pjy, dz = pos[i * 3 + 2] - pjz;
      float d = sqrtf(dx * dx + dy * dy + dz * dz);
      short8 v;
#pragma unroll
      for (int u = 0; u < 8; ++u) {
        float dd = d - cr[u];
        v[u] = f2bf(fexp2(dd * dd * k2[u]));
      }
      AFp[(j * 32 + ic) * 64 + lane] = v;
    }
  } else if (vb < 832) {
    const int idx = vb - 768;
    const int b = idx >> 4, rg = idx & 15;
    const int jj = tid >> 7, h = tid & 127;
    const float* uw1b = upd_w1 + b * 32768 + 16384;
    for (int p = 0; p < 4; ++p) {
      int k = rg * 8 + p * 2 + jj;
      const float* mw2 = msg_w2 + b * 16384 + k * 128;
      float a0 = 0.0f, a1 = 0.0f;
      for (int m = 0; m < 128; m += 2) {
        a0 += mw2[m] * uw1b[m * 128 + h];
        a1 += mw2[m + 1] * uw1b[(m + 1) * 128 + h];
      }
      Wc[b * 16384 + k * 128 + h] = a0 + a1;
    }
  } else if (vb < 836) {
    const int b = vb - 832;
    if (tid < 128) {
      const float* mb2 = msg_b2 + b * 128;
      const float* uw1b = upd_w1 + b * 32768 + 16384;
      float a0 = 0.0f, a1 = 0.0f;
      for (int m = 0; m < 128; m += 2) {
        a0 += mb2[m] * uw1b[m * 128 + tid];
        a1 += mb2[m + 1] * uw1b[(m + 1) * 128 + tid];
      }
      bc[b * 128 + tid] = a0 + a1;
    }
  } else if (vb < 840) {
    const int b = vb - 836;
    const float* w1rb = msg_w1 + b * 188 * 128 + 16384;
    short8* dst = (short8*)(ws + WS_BF) + b * 512;
    for (int slot = tid; slot < 512; slot += 256) {
      int ln = slot & 63, ht = slot >> 6;
      int qd = ln >> 4, l = ln & 15;
      short8 v;
#pragma unroll
      for (int u = 0; u < 8; ++u) {
        int r = qd * 8 + u;
        v[u] = f2bf(w1rb[r * 128 + ht * 16 + l]);
      }
      dst[slot] = v;
    }
  } else if (vb < 844) {
    const int b = vb - 840;
    if (tid < 128) {
      const float* w1rb = msg_w1 + b * 188 * 128 + 16384;
      float acc = 0.0f;
      for (int r = 0; r < KTRUNC; ++r) {
        float c = centers[r], w = widths[r];
        float rb = fexp2(c * c * (-0.7213475204444817f / (w * w)));
        acc += bf2f(f2bf(rb)) * bf2f(f2bf(w1rb[r * 128 + tid]));
      }
      corr[b * 128 + tid] = acc;
    }
  } else {
    for (int idx = tid; idx < 2048; idx += 256) pool[idx] = 0.0f;
  }
}

// msg: htl-OUTER / jj-inner lean loop nest (R7 lesson; live set ~30 VGPR).
// Arithmetic identical to the R4 form (same mfma operands, same silu order,
// same reduce); only the store order changes.
__device__ __attribute__((noinline)) void msg_vblock(
    int vb, int tid, const short8* AFp, const short8* BFb,
    const float* t, float* part)
{
  const int lane = tid & 63, wv = tid >> 6;
  const int quad = lane >> 4, l16 = lane & 15;
  const int jt = vb & 31, is = (vb >> 5) & 31, hh = vb >> 10;
  const int i0 = is * 16;
  const int jb = jt * 16 + wv * 4;
  short8 AFv[4];
#pragma unroll
  for (int jj = 0; jj < 4; ++jj)
    AFv[jj] = AFp[((jb + jj) * 32 + is) * 64 + lane];
#pragma unroll
  for (int htl = 0; htl < 4; ++htl) {
    const short8 Bf = BFb[(hh * 4 + htl) * 64 + lane];
    f32x4 Ct;
#pragma unroll
    for (int r = 0; r < 4; ++r)
      Ct[r] = t[(i0 + quad * 4 + r) * 128 + (hh * 4 + htl) * 16 + l16];
#pragma unroll
    for (int jj = 0; jj < 4; ++jj) {
      f32x4 C = __builtin_amdgcn_mfma_f32_16x16x32_bf16(AFv[jj], Bf, Ct, 0, 0, 0);
      float a = 0.0f;
#pragma unroll
      for (int r = 0; r < 4; ++r) {
        float z = C[r];
        float e = fexp2(z * -1.44269504f);
        a += z * frcp(1.0f + e);
      }
      a += __shfl_down(a, 32, 64);
      a += __shfl_down(a, 16, 64);
      if (lane < 16)
        part[(is * 512 + jb + jj) * 128 + hh * 64 + htl * 16 + l16] = a;
    }
  }
}

// update for one atom j of layer b; 256 threads = 2 k-halves x 128 h.
__device__ __attribute__((noinline)) void update_vblock(
    int j, int tid, int b, float* ws, const int* batch,
    const float* msg_w1, const float* msg_b1,
    const float* upd_w1, const float* upd_b1,
    const float* upd_w2, const float* upd_b2,
    float xs[128], float as[128], float vs[128],
    float ps[2][128])
{
  float* x    = ws + WS_X;
  float* t    = ws + WS_T;
  float* pool = ws + WS_POOL;
  const float* part = ws + WS_PART;
  const float* uw1 = upd_w1 + b * 32768;
  const float* ub1 = upd_b1 + b * 128;
  const float* uw2 = upd_w2 + b * 16384;
  const float* ub2 = upd_b2 + b * 128;
  const float* Wcb = ws + WS_WC + b * 16384;
  const float* bcb = ws + WS_BC + b * 128;
  const float* corb = ws + WS_CORR + b * 128;
  const int h = tid & 127, kh = tid >> 7;
  const int k0 = kh * 64;

  if (kh == 0) xs[h] = x[j * 128 + h];
  float p0 = 0.0f, p1 = 0.0f;
#pragma unroll
  for (int is = kh * 16; is < kh * 16 + 16; is += 2) {
    p0 += part[(is * 512 + j) * 128 + h];
    p1 += part[((is + 1) * 512 + j) * 128 + h];
  }
  ps[kh][h] = p0 + p1;
  __syncthreads();
  if (kh == 0) {
    float tcur = t[j * 128 + h];
    as[h] = ps[0][h] + ps[1][h] - silu_f(tcur + corb[h]);
  }
  __syncthreads();
  float a0 = 0.0f, a1 = 0.0f;
  for (int k = k0; k < k0 + 64; k += 2) {
    a0 += xs[k] * uw1[k * 128 + h] + as[k] * Wcb[k * 128 + h];
    a1 += xs[k + 1] * uw1[(k + 1) * 128 + h] + as[k + 1] * Wcb[(k + 1) * 128 + h];
  }
  ps[kh][h] = a0 + a1;
  __syncthreads();
  if (kh == 0)
    vs[h] = silu_f(511.0f * bcb[h] + ub1[h] + ps[0][h] + ps[1][h]);
  __syncthreads();
  float c0 = 0.0f, c1 = 0.0f;
  for (int k = k0; k < k0 + 64; k += 2) {
    c0 += vs[k] * uw2[k * 128 + h];
    c1 += vs[k + 1] * uw2[(k + 1) * 128 + h];
  }
  ps[kh][h] = c0 + c1;
  __syncthreads();
  if (kh == 0) {
    float xn = xs[h] + ub2[h] + ps[0][h] + ps[1][h];
    x[j * 128 + h] = xn;
    xs[h] = xn;
  }
  __syncthreads();
  if (b < 3) {
    const float* w1x_next = msg_w1 + (b + 1) * 188 * 128;
    const float* b1_next = msg_b1 + (b + 1) * 128;
    float t0 = 0.0f, t1 = 0.0f;
    for (int k = k0; k < k0 + 64; k += 2) {
      t0 += xs[k] * w1x_next[k * 128 + h];
      t1 += xs[k + 1] * w1x_next[(k + 1) * 128 + h];
    }
    ps[kh][h] = t0 + t1;
    __syncthreads();
    if (kh == 0) t[j * 128 + h] = b1_next[h] + ps[0][h] + ps[1][h];
    __syncthreads();
  } else {
    if (kh == 0) atomicAdd(pool + batch[j] * 128 + h, xs[h]);
    __syncthreads();
  }
}

__device__ __attribute__((noinline)) void final_block(
    int tid, const float* pool, const int* batch,
    const float* ow1, const float* ob1,
    const float* ow2, const float* ob2, float* out,
    float pooled[16][128], float h1[16][64], int cnti[16])
{
  if (tid < 16) cnti[tid] = 0;
  __syncthreads();
  atomicAdd(&cnti[batch[tid]], 1);
  atomicAdd(&cnti[batch[tid + 256]], 1);
  __syncthreads();
  for (int idx = tid; idx < 2048; idx += 256) {
    int m = idx >> 7;
    float c = cnti[m] > 0 ? (float)cnti[m] : 1.0f;
    ((float*)pooled)[idx] = pool[idx] / c;
  }
  __syncthreads();
  for (int idx = tid; idx < 1024; idx += 256) {
    int m = idx >> 6, o = idx & 63;
    float a0 = 0.0f, a1 = 0.0f;
    for (int k = 0; k < 128; k += 2) {
      a0 += pooled[m][k] * ow1[k * 64 + o];
      a1 += pooled[m][k + 1] * ow1[(k + 1) * 64 + o];
    }
    h1[m][o] = silu_f(ob1[o] + a0 + a1);
  }
  __syncthreads();
  if (tid < 16) {
    float acc = ob2[0];
    for (int o = 0; o < 64; ++o) acc += h1[tid][o] * ow2[o];
    out[tid] = acc;
  }
}

union SmemT {
  struct { float xl[2][128]; } setup;
  struct { float xs[128], as[128], vs[128], ps[2][128]; } upd;
  struct { float pooled[16][128]; float h1[16][64]; int cnti[16]; } fin;
};

// ===========================================================================
// Path A: single persistent kernel, NO min-waves coercion (R7/R9: coercion
// spills). noinline phases shrink the natural register footprint; the
// nb={3,2,1} ladder discovers whatever co-residency the allocation permits.
// ===========================================================================
__global__ __launch_bounds__(256) void fused_kernel(
    const int* an, const float* pos, const int* batch, const float* emb,
    const float* centers, const float* widths,
    const float* msg_w1, const float* msg_b1,
    const float* msg_w2, const float* msg_b2,
    const float* upd_w1, const float* upd_b1,
    const float* upd_w2, const float* upd_b2,
    const float* ow1, const float* ob1, const float* ow2, const float* ob2,
    float* ws, float* out)
{
  __shared__ SmemT sm;
  __shared__ unsigned lastflag;
  const int bid = blockIdx.x, tid = threadIdx.x;
  const short8* AFp = (const short8*)(ws + WS_AF);
  const short8* BFp = (const short8*)(ws + WS_BF);
  unsigned* bar = (unsigned*)(ws + WS_BAR);
  float* part = ws + WS_PART;
  float* t = ws + WS_T;

  for (int vb = bid; vb < 845; vb += gridDim.x)
    setup_vblock(vb, tid, an, pos, emb, msg_w1, msg_b1, msg_w2, msg_b2,
                 upd_w1, centers, widths, ws, sm.setup.xl);
  grid_barrier(bar, 0);

  for (int b = 0; b < 4; ++b) {
    const short8* BFb = BFp + b * 512;
    for (int vb = bid; vb < 2048; vb += gridDim.x)
      msg_vblock(vb, tid, AFp, BFb, t, part);
    grid_barrier(bar, 1 + 2 * b);
    for (int vb = bid; vb < 512; vb += gridDim.x)
      update_vblock(vb, tid, b, ws, batch, msg_w1, msg_b1,
                    upd_w1, upd_b1, upd_w2, upd_b2,
                    sm.upd.xs, sm.upd.as, sm.upd.vs, sm.upd.ps);
    if (b < 3) grid_barrier(bar, 2 + 2 * b);
  }

  // done-counter replaces the 9th barrier: last block runs the final MLP
  __syncthreads();
  if (tid == 0) {
    __threadfence();
    unsigned old = atomicAdd(&bar[248], 1u);
    lastflag = (old - 0xAAAAAAAAu == gridDim.x - 1) ? 1u : 0u;
  }
  __syncthreads();
  if (lastflag) {
    __threadfence();
    final_block(tid, ws + WS_POOL, batch, ow1, ob1, ow2, ob2, out,
                sm.fin.pooled, sm.fin.h1, sm.fin.cnti);
  }
}

// ===========================================================================
// Path B: split kernels (fallback — R7-proven shapes)
// ===========================================================================
__global__ __launch_bounds__(256) void setup_kernel(
    const int* an, const float* pos, const float* emb,
    const float* msg_w1, const float* msg_b1, const float* msg_w2,
    const float* msg_b2, const float* upd_w1,
    const float* centers, const float* widths, float* ws)
{
  __shared__ float xl[2][128];
  setup_vblock(blockIdx.x, threadIdx.x, an, pos, emb, msg_w1, msg_b1,
               msg_w2, msg_b2, upd_w1, centers, widths, ws, xl);
}

__global__ __launch_bounds__(256) void msg_kernel(
    const short8* AF, const short8* BF, const float* t, float* part)
{
  msg_vblock(blockIdx.x, threadIdx.x, AF, BF, t, part);
}

__global__ __launch_bounds__(256) void update_kernel(
    float* ws, const int* batch, int b,
    const float* msg_w1, const float* msg_b1,
    const float* upd_w1, const float* upd_b1,
    const float* upd_w2, const float* upd_b2)
{
  __shared__ float xs[128], as[128], vs[128], ps[2][128];
  update_vblock(blockIdx.x, threadIdx.x, b, ws, batch, msg_w1, msg_b1,
                upd_w1, upd_b1, upd_w2, upd_b2, xs, as, vs, ps);
}

__global__ __launch_bounds__(256) void final_kernel(
    const float* pool, const int* batch,
    const float* ow1, const float* ob1,
    const float* ow2, const float* ob2, float* out)
{
  __shared__ float pooled[16][128];
  __shared__ float h1[16][64];
  __shared__ int cnti[16];
  final_block(threadIdx.x, pool, batch, ow1, ob1, ow2, ob2, out,
              pooled, h1, cnti);
}

// ===========================================================================
// Lazy runtime probe (first eager kernel_launch call only). Ladder nb=3,2,1
// each sentinel-verified with fresh bar poison; nb=1 is the R4-proven floor
// (207us). Failed rungs cost ~1.1s each (R7/R9 measured). Any full failure
// -> split path forever.
// ===========================================================================
static int g_mode = 0;  // 0 = unprobed, 1 = fused, 2 = split
static int g_nb = 1;

extern "C" void kernel_launch(void* const* d_in, const int* in_sizes, int n_in,
                              void* d_out, int out_size, void* d_ws, size_t ws_size,
                              hipStream_t stream) {
  const int*   an      = (const int*)d_in[0];
  const float* pos     = (const float*)d_in[1];
  const int*   batch   = (const int*)d_in[2];
  const float* emb     = (const float*)d_in[3];
  const float* centers = (const float*)d_in[4];
  const float* widths  = (const float*)d_in[5];
  const float* msg_w1  = (const float*)d_in[6];
  const float* msg_b1  = (const float*)d_in[7];
  const float* msg_w2  = (const float*)d_in[8];
  const float* msg_b2  = (const float*)d_in[9];
  const float* upd_w1  = (const float*)d_in[10];
  const float* upd_b1  = (const float*)d_in[11];
  const float* upd_w2  = (const float*)d_in[12];
  const float* upd_b2  = (const float*)d_in[13];
  const float* ow1     = (const float*)d_in[14];
  const float* ob1     = (const float*)d_in[15];
  const float* ow2     = (const float*)d_in[16];
  const float* ob2     = (const float*)d_in[17];
  float* ws  = (float*)d_ws;
  float* out = (float*)d_out;

  if (g_mode == 0) {
    hipStreamCaptureStatus st = hipStreamCaptureStatusNone;
    (void)hipStreamIsCapturing(stream, &st);
    if (st != hipStreamCaptureStatusNone) {
      g_mode = 2;  // first call under capture: take the safe path forever
    } else {
      (void)hipGetLastError();  // flush stale errors
      static unsigned hflag;
      const int tries_nb[3] = {3, 2, 1};
      for (int attempt = 0; attempt < 3 && g_mode == 0; ++attempt) {
        int nb = tries_nb[attempt];
        // restore barrier-counter poison (harness poisons only once per call)
        bool good = hipMemsetAsync((char*)d_ws + (size_t)WS_BAR * 4, 0xAA,
                                   256 * 4, stream) == hipSuccess;
        if (good) {
          dim3 grid(256 * nb), block(256);
          hipLaunchKernelGGL(fused_kernel, grid, block, 0, stream,
                             an, pos, batch, emb, centers, widths,
                             msg_w1, msg_b1, msg_w2, msg_b2,
                             upd_w1, upd_b1, upd_w2, upd_b2,
                             ow1, ob1, ow2, ob2, ws, out);
          good = hipGetLastError() == hipSuccess;
        }
        hflag = 0;
        if (good)
          good = hipMemcpyAsync(&hflag, (char*)d_ws + (size_t)(WS_BAR + 252) * 4,
                                4, hipMemcpyDeviceToHost, stream) == hipSuccess;
        if (good) good = hipStreamSynchronize(stream) == hipSuccess;
        if (good && hflag != 0xDEADBEEFu) {
          g_mode = 1;
          g_nb = nb;
          return;  // fused output already produced for this call
        }
        (void)hipGetLastError();
        (void)hipStreamSynchronize(stream);
        (void)hipGetLastError();
      }
      if (g_mode == 0) g_mode = 2;  // all attempts failed: split forever
      // fall through: split path recomputes everything safely
    }
  }

  if (g_mode == 1) {
    dim3 grid(256 * g_nb), block(256);
    hipLaunchKernelGGL(fused_kernel, grid, block, 0, stream,
                       an, pos, batch, emb, centers, widths,
                       msg_w1, msg_b1, msg_w2, msg_b2,
                       upd_w1, upd_b1, upd_w2, upd_b2,
                       ow1, ob1, ow2, ob2, ws, out);
    return;
  }

  // Split-dispatch path (R7-proven shapes)
  const short8* AFp = (const short8*)(ws + WS_AF);
  const short8* BFp = (const short8*)(ws + WS_BF);
  setup_kernel<<<dim3(845), dim3(256), 0, stream>>>(
      an, pos, emb, msg_w1, msg_b1, msg_w2, msg_b2, upd_w1, centers, widths, ws);
  for (int b = 0; b < 4; ++b) {
    msg_kernel<<<dim3(2048), dim3(256), 0, stream>>>(
        AFp, BFp + b * 512, ws + WS_T, ws + WS_PART);
    update_kernel<<<dim3(512), dim3(256), 0, stream>>>(
        ws, batch, b, msg_w1, msg_b1, upd_w1, upd_b1, upd_w2, upd_b2);
  }
  final_kernel<<<dim3(1), dim3(256), 0, stream>>>(
      ws + WS_POOL, batch, ow1, ob1, ow2, ob2, out);
}

// Round 15
// 521.478 us; speedup vs baseline: 1.2676x; 1.2676x over previous
//
#include <hip/hip_runtime.h>
#include <hip/hip_bf16.h>
#include <chrono>

#define NRBF 60
#define KTRUNC 32          // rbf r>=32 is < 1.4e-13 for d <= sqrt(3) < cutoff

// ws float offsets (unified layout for both paths)
#define WS_X      0          // 512*128
#define WS_T      65536      // 512*128
#define WS_WC     131072     // 4*128*128
#define WS_BC     196608     // 4*128
#define WS_CORR   197120     // 4*128
#define WS_POOL   197632     // 16*128
#define WS_BAR    199680     // 8 barrier counters*32 u32 + done ctr + fail flag (256 u32)
#define WS_BF     199936     // 4 layers * 512 short8 (8192 floats)
#define WS_PART   208128     // 32*512*128 partials (2097152 floats)
#define WS_AF     2305280    // 512*32*64 short8 (4194304 floats) = 16.8 MB
#define WS_TOTALF 6499584    // floats

typedef short short8 __attribute__((ext_vector_type(8)));
typedef float f32x4 __attribute__((ext_vector_type(4)));

__device__ inline float fexp2(float x) { return __builtin_amdgcn_exp2f(x); }
__device__ inline float frcp(float x) { return __builtin_amdgcn_rcpf(x); }
__device__ inline float silu_f(float z) {
  float e = fexp2(z * -1.44269504f);
  return z * frcp(1.0f + e);
}
__device__ inline short f2bf(float f) {
  unsigned u = __float_as_uint(f);
  unsigned r = (u + 0x7FFFu + ((u >> 16) & 1u)) >> 16;
  return (short)r;
}
__device__ inline float bf2f(short b) {
  unsigned u = ((unsigned)(unsigned short)b) << 16;
  return __uint_as_float(u);
}

// ---------------------------------------------------------------------------
// Sharded grid barrier. Counters live in ws, poisoned to 0xAAAAAAAA before
// every attempt -> arrivals = load - 0xAAAAAAAA. 8 shards, 128B apart.
// Plain atomic spin barrier — needs co-residency only. On timeout writes a
// sentinel to bar[252] so the host probe can detect failure.
// ---------------------------------------------------------------------------
__device__ inline void grid_barrier(unsigned* bar, int seq) {
  __syncthreads();
  if (threadIdx.x == 0) {
    __threadfence();
    atomicAdd(&bar[(blockIdx.x & 7) * 32], 1u);
  }
  if (threadIdx.x < 8) {
    const unsigned cnt = (gridDim.x - threadIdx.x + 7) >> 3;
    const unsigned tgt = (unsigned)(seq + 1) * cnt;
    unsigned tries = 0;
    while ((__hip_atomic_load(&bar[threadIdx.x * 32], __ATOMIC_RELAXED,
                              __HIP_MEMORY_SCOPE_AGENT) -
            0xAAAAAAAAu) < tgt) {
      if (++tries > 1000000u) {  // fail-visible, never hang
        __hip_atomic_store(&bar[252], 0xDEADBEEFu, __ATOMIC_RELAXED,
                           __HIP_MEMORY_SCOPE_AGENT);
        break;
      }
      __builtin_amdgcn_s_sleep(1);
    }
  }
  __threadfence();
  __syncthreads();
}

// ===========================================================================
// Shared device phase helpers. noinline keeps the kernel's register
// footprint ~= max(per-phase) — VGPR 112, spill-free (R13 confirmed:
// WRITE_SIZE back to 52MB). R13 ALSO refuted the occupancy theory:
// nb=2 (Occ 23.6%, clean) is 3x SLOWER than nb=1 regardless of spills
// (R7 687us / R9 651us / R13 661us vs R4 207us) — so the probe below
// now TIMES each grid size and locks the argmin.
// ===========================================================================
__device__ __attribute__((noinline)) void setup_vblock(
    int vb, int tid, const int* an, const float* pos,
    const float* emb, const float* msg_w1,
    const float* msg_b1, const float* msg_w2,
    const float* msg_b2, const float* upd_w1,
    const float* centers, const float* widths,
    float* ws, float xl[2][128])
{
  float* x    = ws + WS_X;
  float* t    = ws + WS_T;
  float* Wc   = ws + WS_WC;
  float* bc   = ws + WS_BC;
  float* corr = ws + WS_CORR;
  float* pool = ws + WS_POOL;
  const int lane = tid & 63;
  const int quad = lane >> 4, l16 = lane & 15;

  if (vb < 256) {
    const int jj = tid >> 7, h = tid & 127;
    const int i = vb * 2 + jj;
    int a = an[i]; a = a < 0 ? 0 : (a > 99 ? 99 : a);
    float xv = emb[a * 128 + h];
    x[i * 128 + h] = xv;
    xl[jj][h] = xv;
    __syncthreads();
    float a0 = 0.0f, a1 = 0.0f;
    for (int k = 0; k < 128; k += 2) {
      a0 += xl[jj][k] * msg_w1[k * 128 + h];
      a1 += xl[jj][k + 1] * msg_w1[(k + 1) * 128 + h];
    }
    t[i * 128 + h] = msg_b1[h] + a0 + a1;
    __syncthreads();
  } else if (vb < 768) {
    const int j = vb - 256;
    const int g = tid >> 6;
    const float pjx = pos[j * 3], pjy = pos[j * 3 + 1], pjz = pos[j * 3 + 2];
    float cr[8], k2[8];
#pragma unroll
    for (int u = 0; u < 8; ++u) {
      int r = quad * 8 + u;
      float w = widths[r];
      cr[u] = centers[r];
      k2[u] = -0.7213475204444817f / (w * w);
    }
    short8* AFp = (short8*)(ws + WS_AF);
    for (int iter = 0; iter < 8; ++iter) {
      int ic = iter * 4 + g;
      int i = ic * 16 + l16;
      float dx = pos[i * 3] - pjx, dy = pos[i * 3 + 1] - pjy, dz = pos[i * 3 + 2] - pjz;
      float d = sqrtf(dx * dx + dy * dy + dz * dz);
      short8 v;
#pragma unroll
      for (int u = 0; u < 8; ++u) {
        float dd = d - cr[u];
        v[u] = f2bf(fexp2(dd * dd * k2[u]));
      }
      AFp[(j * 32 + ic) * 64 + lane] = v;
    }
  } else if (vb < 832) {
    const int idx = vb - 768;
    const int b = idx >> 4, rg = idx & 15;
    const int jj = tid >> 7, h = tid & 127;
    const float* uw1b = upd_w1 + b * 32768 + 16384;
    for (int p = 0; p < 4; ++p) {
      int k = rg * 8 + p * 2 + jj;
      const float* mw2 = msg_w2 + b * 16384 + k * 128;
      float a0 = 0.0f, a1 = 0.0f;
      for (int m = 0; m < 128; m += 2) {
        a0 += mw2[m] * uw1b[m * 128 + h];
        a1 += mw2[m + 1] * uw1b[(m + 1) * 128 + h];
      }
      Wc[b * 16384 + k * 128 + h] = a0 + a1;
    }
  } else if (vb < 836) {
    const int b = vb - 832;
    if (tid < 128) {
      const float* mb2 = msg_b2 + b * 128;
      const float* uw1b = upd_w1 + b * 32768 + 16384;
      float a0 = 0.0f, a1 = 0.0f;
      for (int m = 0; m < 128; m += 2) {
        a0 += mb2[m] * uw1b[m * 128 + tid];
        a1 += mb2[m + 1] * uw1b[(m + 1) * 128 + tid];
      }
      bc[b * 128 + tid] = a0 + a1;
    }
  } else if (vb < 840) {
    const int b = vb - 836;
    const float* w1rb = msg_w1 + b * 188 * 128 + 16384;
    short8* dst = (short8*)(ws + WS_BF) + b * 512;
    for (int slot = tid; slot < 512; slot += 256) {
      int ln = slot & 63, ht = slot >> 6;
      int qd = ln >> 4, l = ln & 15;
      short8 v;
#pragma unroll
      for (int u = 0; u < 8; ++u) {
        int r = qd * 8 + u;
        v[u] = f2bf(w1rb[r * 128 + ht * 16 + l]);
      }
      dst[slot] = v;
    }
  } else if (vb < 844) {
    const int b = vb - 840;
    if (tid < 128) {
      const float* w1rb = msg_w1 + b * 188 * 128 + 16384;
      float acc = 0.0f;
      for (int r = 0; r < KTRUNC; ++r) {
        float c = centers[r], w = widths[r];
        float rb = fexp2(c * c * (-0.7213475204444817f / (w * w)));
        acc += bf2f(f2bf(rb)) * bf2f(f2bf(w1rb[r * 128 + tid]));
      }
      corr[b * 128 + tid] = acc;
    }
  } else {
    for (int idx = tid; idx < 2048; idx += 256) pool[idx] = 0.0f;
  }
}

// msg: htl-OUTER / jj-inner lean loop nest (live set ~30 VGPR).
__device__ __attribute__((noinline)) void msg_vblock(
    int vb, int tid, const short8* AFp, const short8* BFb,
    const float* t, float* part)
{
  const int lane = tid & 63, wv = tid >> 6;
  const int quad = lane >> 4, l16 = lane & 15;
  const int jt = vb & 31, is = (vb >> 5) & 31, hh = vb >> 10;
  const int i0 = is * 16;
  const int jb = jt * 16 + wv * 4;
  short8 AFv[4];
#pragma unroll
  for (int jj = 0; jj < 4; ++jj)
    AFv[jj] = AFp[((jb + jj) * 32 + is) * 64 + lane];
#pragma unroll
  for (int htl = 0; htl < 4; ++htl) {
    const short8 Bf = BFb[(hh * 4 + htl) * 64 + lane];
    f32x4 Ct;
#pragma unroll
    for (int r = 0; r < 4; ++r)
      Ct[r] = t[(i0 + quad * 4 + r) * 128 + (hh * 4 + htl) * 16 + l16];
#pragma unroll
    for (int jj = 0; jj < 4; ++jj) {
      f32x4 C = __builtin_amdgcn_mfma_f32_16x16x32_bf16(AFv[jj], Bf, Ct, 0, 0, 0);
      float a = 0.0f;
#pragma unroll
      for (int r = 0; r < 4; ++r) {
        float z = C[r];
        float e = fexp2(z * -1.44269504f);
        a += z * frcp(1.0f + e);
      }
      a += __shfl_down(a, 32, 64);
      a += __shfl_down(a, 16, 64);
      if (lane < 16)
        part[(is * 512 + jb + jj) * 128 + hh * 64 + htl * 16 + l16] = a;
    }
  }
}

// update for one atom j of layer b; 256 threads = 2 k-halves x 128 h.
__device__ __attribute__((noinline)) void update_vblock(
    int j, int tid, int b, float* ws, const int* batch,
    const float* msg_w1, const float* msg_b1,
    const float* upd_w1, const float* upd_b1,
    const float* upd_w2, const float* upd_b2,
    float xs[128], float as[128], float vs[128],
    float ps[2][128])
{
  float* x    = ws + WS_X;
  float* t    = ws + WS_T;
  float* pool = ws + WS_POOL;
  const float* part = ws + WS_PART;
  const float* uw1 = upd_w1 + b * 32768;
  const float* ub1 = upd_b1 + b * 128;
  const float* uw2 = upd_w2 + b * 16384;
  const float* ub2 = upd_b2 + b * 128;
  const float* Wcb = ws + WS_WC + b * 16384;
  const float* bcb = ws + WS_BC + b * 128;
  const float* corb = ws + WS_CORR + b * 128;
  const int h = tid & 127, kh = tid >> 7;
  const int k0 = kh * 64;

  if (kh == 0) xs[h] = x[j * 128 + h];
  float p0 = 0.0f, p1 = 0.0f;
#pragma unroll
  for (int is = kh * 16; is < kh * 16 + 16; is += 2) {
    p0 += part[(is * 512 + j) * 128 + h];
    p1 += part[((is + 1) * 512 + j) * 128 + h];
  }
  ps[kh][h] = p0 + p1;
  __syncthreads();
  if (kh == 0) {
    float tcur = t[j * 128 + h];
    as[h] = ps[0][h] + ps[1][h] - silu_f(tcur + corb[h]);
  }
  __syncthreads();
  float a0 = 0.0f, a1 = 0.0f;
  for (int k = k0; k < k0 + 64; k += 2) {
    a0 += xs[k] * uw1[k * 128 + h] + as[k] * Wcb[k * 128 + h];
    a1 += xs[k + 1] * uw1[(k + 1) * 128 + h] + as[k + 1] * Wcb[(k + 1) * 128 + h];
  }
  ps[kh][h] = a0 + a1;
  __syncthreads();
  if (kh == 0)
    vs[h] = silu_f(511.0f * bcb[h] + ub1[h] + ps[0][h] + ps[1][h]);
  __syncthreads();
  float c0 = 0.0f, c1 = 0.0f;
  for (int k = k0; k < k0 + 64; k += 2) {
    c0 += vs[k] * uw2[k * 128 + h];
    c1 += vs[k + 1] * uw2[(k + 1) * 128 + h];
  }
  ps[kh][h] = c0 + c1;
  __syncthreads();
  if (kh == 0) {
    float xn = xs[h] + ub2[h] + ps[0][h] + ps[1][h];
    x[j * 128 + h] = xn;
    xs[h] = xn;
  }
  __syncthreads();
  if (b < 3) {
    const float* w1x_next = msg_w1 + (b + 1) * 188 * 128;
    const float* b1_next = msg_b1 + (b + 1) * 128;
    float t0 = 0.0f, t1 = 0.0f;
    for (int k = k0; k < k0 + 64; k += 2) {
      t0 += xs[k] * w1x_next[k * 128 + h];
      t1 += xs[k + 1] * w1x_next[(k + 1) * 128 + h];
    }
    ps[kh][h] = t0 + t1;
    __syncthreads();
    if (kh == 0) t[j * 128 + h] = b1_next[h] + ps[0][h] + ps[1][h];
    __syncthreads();
  } else {
    if (kh == 0) atomicAdd(pool + batch[j] * 128 + h, xs[h]);
    __syncthreads();
  }
}

__device__ __attribute__((noinline)) void final_block(
    int tid, const float* pool, const int* batch,
    const float* ow1, const float* ob1,
    const float* ow2, const float* ob2, float* out,
    float pooled[16][128], float h1[16][64], int cnti[16])
{
  if (tid < 16) cnti[tid] = 0;
  __syncthreads();
  atomicAdd(&cnti[batch[tid]], 1);
  atomicAdd(&cnti[batch[tid + 256]], 1);
  __syncthreads();
  for (int idx = tid; idx < 2048; idx += 256) {
    int m = idx >> 7;
    float c = cnti[m] > 0 ? (float)cnti[m] : 1.0f;
    ((float*)pooled)[idx] = pool[idx] / c;
  }
  __syncthreads();
  for (int idx = tid; idx < 1024; idx += 256) {
    int m = idx >> 6, o = idx & 63;
    float a0 = 0.0f, a1 = 0.0f;
    for (int k = 0; k < 128; k += 2) {
      a0 += pooled[m][k] * ow1[k * 64 + o];
      a1 += pooled[m][k + 1] * ow1[(k + 1) * 64 + o];
    }
    h1[m][o] = silu_f(ob1[o] + a0 + a1);
  }
  __syncthreads();
  if (tid < 16) {
    float acc = ob2[0];
    for (int o = 0; o < 64; ++o) acc += h1[tid][o] * ow2[o];
    out[tid] = acc;
  }
}

union SmemT {
  struct { float xl[2][128]; } setup;
  struct { float xs[128], as[128], vs[128], ps[2][128]; } upd;
  struct { float pooled[16][128]; float h1[16][64]; int cnti[16]; } fin;
};

// ===========================================================================
// Path A: single persistent kernel (no launch_bounds coercion).
// ===========================================================================
__global__ __launch_bounds__(256) void fused_kernel(
    const int* an, const float* pos, const int* batch, const float* emb,
    const float* centers, const float* widths,
    const float* msg_w1, const float* msg_b1,
    const float* msg_w2, const float* msg_b2,
    const float* upd_w1, const float* upd_b1,
    const float* upd_w2, const float* upd_b2,
    const float* ow1, const float* ob1, const float* ow2, const float* ob2,
    float* ws, float* out)
{
  __shared__ SmemT sm;
  __shared__ unsigned lastflag;
  const int bid = blockIdx.x, tid = threadIdx.x;
  const short8* AFp = (const short8*)(ws + WS_AF);
  const short8* BFp = (const short8*)(ws + WS_BF);
  unsigned* bar = (unsigned*)(ws + WS_BAR);
  float* part = ws + WS_PART;
  float* t = ws + WS_T;

  for (int vb = bid; vb < 845; vb += gridDim.x)
    setup_vblock(vb, tid, an, pos, emb, msg_w1, msg_b1, msg_w2, msg_b2,
                 upd_w1, centers, widths, ws, sm.setup.xl);
  grid_barrier(bar, 0);

  for (int b = 0; b < 4; ++b) {
    const short8* BFb = BFp + b * 512;
    for (int vb = bid; vb < 2048; vb += gridDim.x)
      msg_vblock(vb, tid, AFp, BFb, t, part);
    grid_barrier(bar, 1 + 2 * b);
    for (int vb = bid; vb < 512; vb += gridDim.x)
      update_vblock(vb, tid, b, ws, batch, msg_w1, msg_b1,
                    upd_w1, upd_b1, upd_w2, upd_b2,
                    sm.upd.xs, sm.upd.as, sm.upd.vs, sm.upd.ps);
    if (b < 3) grid_barrier(bar, 2 + 2 * b);
  }

  // done-counter replaces the 9th barrier: last block runs the final MLP
  __syncthreads();
  if (tid == 0) {
    __threadfence();
    unsigned old = atomicAdd(&bar[248], 1u);
    lastflag = (old - 0xAAAAAAAAu == gridDim.x - 1) ? 1u : 0u;
  }
  __syncthreads();
  if (lastflag) {
    __threadfence();
    final_block(tid, ws + WS_POOL, batch, ow1, ob1, ow2, ob2, out,
                sm.fin.pooled, sm.fin.h1, sm.fin.cnti);
  }
}

// ===========================================================================
// Path B: split kernels (fallback — R7-proven shapes)
// ===========================================================================
__global__ __launch_bounds__(256) void setup_kernel(
    const int* an, const float* pos, const float* emb,
    const float* msg_w1, const float* msg_b1, const float* msg_w2,
    const float* msg_b2, const float* upd_w1,
    const float* centers, const float* widths, float* ws)
{
  __shared__ float xl[2][128];
  setup_vblock(blockIdx.x, threadIdx.x, an, pos, emb, msg_w1, msg_b1,
               msg_w2, msg_b2, upd_w1, centers, widths, ws, xl);
}

__global__ __launch_bounds__(256) void msg_kernel(
    const short8* AF, const short8* BF, const float* t, float* part)
{
  msg_vblock(blockIdx.x, threadIdx.x, AF, BF, t, part);
}

__global__ __launch_bounds__(256) void update_kernel(
    float* ws, const int* batch, int b,
    const float* msg_w1, const float* msg_b1,
    const float* upd_w1, const float* upd_b1,
    const float* upd_w2, const float* upd_b2)
{
  __shared__ float xs[128], as[128], vs[128], ps[2][128];
  update_vblock(blockIdx.x, threadIdx.x, b, ws, batch, msg_w1, msg_b1,
                upd_w1, upd_b1, upd_w2, upd_b2, xs, as, vs, ps);
}

__global__ __launch_bounds__(256) void final_kernel(
    const float* pool, const int* batch,
    const float* ow1, const float* ob1,
    const float* ow2, const float* ob2, float* out)
{
  __shared__ float pooled[16][128];
  __shared__ float h1[16][64];
  __shared__ int cnti[16];
  final_block(threadIdx.x, pool, batch, ow1, ob1, ow2, ob2, out,
              pooled, h1, cnti);
}

// ===========================================================================
// Lazy runtime TIMED probe (first eager kernel_launch call only).
// R13 lesson: "first passing rung" locked nb=2, which is 3x SLOWER than
// nb=1 (661 vs 207us) despite 2x occupancy and clean traffic — so the probe
// now wall-clock-times each candidate {2,1} (launch+sync, chrono) and locks
// the argmin among sentinel-clean runs. Each probe launch fully
// reinitializes ws (setup rewrites x/t/Wc/bc/corr/BF/AF, zeroes pool; bar
// re-poisoned via memset), so sequential launches are safe and the last
// passing launch's output is valid. Any full failure -> split path forever.
// ===========================================================================
static int g_mode = 0;  // 0 = unprobed, 1 = fused, 2 = split
static int g_nb = 1;

extern "C" void kernel_launch(void* const* d_in, const int* in_sizes, int n_in,
                              void* d_out, int out_size, void* d_ws, size_t ws_size,
                              hipStream_t stream) {
  const int*   an      = (const int*)d_in[0];
  const float* pos     = (const float*)d_in[1];
  const int*   batch   = (const int*)d_in[2];
  const float* emb     = (const float*)d_in[3];
  const float* centers = (const float*)d_in[4];
  const float* widths  = (const float*)d_in[5];
  const float* msg_w1  = (const float*)d_in[6];
  const float* msg_b1  = (const float*)d_in[7];
  const float* msg_w2  = (const float*)d_in[8];
  const float* msg_b2  = (const float*)d_in[9];
  const float* upd_w1  = (const float*)d_in[10];
  const float* upd_b1  = (const float*)d_in[11];
  const float* upd_w2  = (const float*)d_in[12];
  const float* upd_b2  = (const float*)d_in[13];
  const float* ow1     = (const float*)d_in[14];
  const float* ob1     = (const float*)d_in[15];
  const float* ow2     = (const float*)d_in[16];
  const float* ob2     = (const float*)d_in[17];
  float* ws  = (float*)d_ws;
  float* out = (float*)d_out;

  if (g_mode == 0) {
    hipStreamCaptureStatus st = hipStreamCaptureStatusNone;
    (void)hipStreamIsCapturing(stream, &st);
    if (st != hipStreamCaptureStatusNone) {
      g_mode = 2;  // first call under capture: take the safe path forever
    } else {
      (void)hipGetLastError();  // flush stale errors
      static unsigned hflag;
      const int cand_nb[2] = {2, 1};
      double best_t = 1e30;
      int best_nb = 0;
      for (int attempt = 0; attempt < 2; ++attempt) {
        int nb = cand_nb[attempt];
        // restore barrier-counter poison (harness poisons only once per call)
        bool good = hipMemsetAsync((char*)d_ws + (size_t)WS_BAR * 4, 0xAA,
                                   256 * 4, stream) == hipSuccess;
        if (good) good = hipStreamSynchronize(stream) == hipSuccess;
        auto t0 = std::chrono::steady_clock::now();
        if (good) {
          dim3 grid(256 * nb), block(256);
          hipLaunchKernelGGL(fused_kernel, grid, block, 0, stream,
                             an, pos, batch, emb, centers, widths,
                             msg_w1, msg_b1, msg_w2, msg_b2,
                             upd_w1, upd_b1, upd_w2, upd_b2,
                             ow1, ob1, ow2, ob2, ws, out);
          good = hipGetLastError() == hipSuccess;
        }
        if (good) good = hipStreamSynchronize(stream) == hipSuccess;
        auto t1 = std::chrono::steady_clock::now();
        hflag = 0;
        if (good)
          good = hipMemcpyAsync(&hflag, (char*)d_ws + (size_t)(WS_BAR + 252) * 4,
                                4, hipMemcpyDeviceToHost, stream) == hipSuccess;
        if (good) good = hipStreamSynchronize(stream) == hipSuccess;
        if (good && hflag != 0xDEADBEEFu) {
          double dt = std::chrono::duration<double>(t1 - t0).count();
          if (dt < best_t) { best_t = dt; best_nb = nb; }
        } else {
          (void)hipGetLastError();
          (void)hipStreamSynchronize(stream);
          (void)hipGetLastError();
        }
      }
      if (best_nb > 0) {
        g_mode = 1;
        g_nb = best_nb;
        // out already holds a valid result from the last passing launch;
        // if the last rung failed but an earlier one passed, relaunch best.
        if (hflag == 0xDEADBEEFu) {
          (void)hipMemsetAsync((char*)d_ws + (size_t)WS_BAR * 4, 0xAA,
                               256 * 4, stream);
          dim3 grid(256 * g_nb), block(256);
          hipLaunchKernelGGL(fused_kernel, grid, block, 0, stream,
                             an, pos, batch, emb, centers, widths,
                             msg_w1, msg_b1, msg_w2, msg_b2,
                             upd_w1, upd_b1, upd_w2, upd_b2,
                             ow1, ob1, ow2, ob2, ws, out);
          (void)hipStreamSynchronize(stream);
        }
        return;
      }
      g_mode = 2;  // all candidates failed: split forever
      // fall through: split path recomputes everything safely
    }
  }

  if (g_mode == 1) {
    dim3 grid(256 * g_nb), block(256);
    hipLaunchKernelGGL(fused_kernel, grid, block, 0, stream,
                       an, pos, batch, emb, centers, widths,
                       msg_w1, msg_b1, msg_w2, msg_b2,
                       upd_w1, upd_b1, upd_w2, upd_b2,
                       ow1, ob1, ow2, ob2, ws, out);
    return;
  }

  // Split-dispatch path (R7-proven shapes)
  const short8* AFp = (const short8*)(ws + WS_AF);
  const short8* BFp = (const short8*)(ws + WS_BF);
  setup_kernel<<<dim3(845), dim3(256), 0, stream>>>(
      an, pos, emb, msg_w1, msg_b1, msg_w2, msg_b2, upd_w1, centers, widths, ws);
  for (int b = 0; b < 4; ++b) {
    msg_kernel<<<dim3(2048), dim3(256), 0, stream>>>(
        AFp, BFp + b * 512, ws + WS_T, ws + WS_PART);
    update_kernel<<<dim3(512), dim3(256), 0, stream>>>(
        ws, batch, b, msg_w1, msg_b1, upd_w1, upd_b1, upd_w2, upd_b2);
  }
  final_kernel<<<dim3(1), dim3(256), 0, stream>>>(
      ws + WS_POOL, batch, ow1, ob1, ow2, ob2, out);
}

// Round 17
// 216.192 us; speedup vs baseline: 3.0576x; 2.4121x over previous
//
#include <hip/hip_runtime.h>
#include <hip/hip_bf16.h>

#define NRBF 60
#define KTRUNC 32          // rbf r>=32 is < 1.4e-13 for d <= sqrt(3) < cutoff

// ws float offsets
#define WS_X      0          // 512*128
#define WS_T      65536      // 512*128
#define WS_WC     131072     // 4*128*128
#define WS_BC     196608     // 4*128
#define WS_CORR   197120     // 4*128
#define WS_POOL   197632     // 16*128
#define WS_BAR    199680     // done-counter region (256 u32, harness-poisoned 0xAAAAAAAA)
#define WS_BF     199936     // 4 layers * 512 short8 (8192 floats)
#define WS_PART   208128     // 32*512*128 partials (2097152 floats)
#define WS_AF     2305280    // 512*32*64 short8 (4194304 floats) = 16.8 MB
#define WS_TOTALF 6499584    // floats

typedef short short8 __attribute__((ext_vector_type(8)));
typedef float f32x4 __attribute__((ext_vector_type(4)));

__device__ inline float fexp2(float x) { return __builtin_amdgcn_exp2f(x); }
__device__ inline float frcp(float x) { return __builtin_amdgcn_rcpf(x); }
__device__ inline float silu_f(float z) {
  float e = fexp2(z * -1.44269504f);
  return z * frcp(1.0f + e);
}
__device__ inline short f2bf(float f) {
  unsigned u = __float_as_uint(f);
  unsigned r = (u + 0x7FFFu + ((u >> 16) & 1u)) >> 16;
  return (short)r;
}
__device__ inline float bf2f(short b) {
  unsigned u = ((unsigned)(unsigned short)b) << 16;
  return __uint_as_float(u);
}

// ===========================================================================
// SPLIT PATH ONLY. Session ledger (timed): split=206us; fused inline nb=1
// =207 (tie); fused noinline nb=1 =521; fused nb=2 (any) =651-687. The
// persistent-kernel branch never beat split -> launch boundaries are NOT
// the cost; fused machinery removed. This round: merge final into
// update(b=3) via done-counter (10 -> 9 dispatches, kills 1-block tail).
// ===========================================================================

// ---------------------------------------------------------------------------
// setup: one vblock per block (845 blocks). Phases: x/t (256), AF rbf build
// (512), Wc precompute (64), bc (4), BF bf16 weights (4), corr (4), pool
// zero (1). R7-session-proven shapes, inline bodies.
// ---------------------------------------------------------------------------
__global__ __launch_bounds__(256) void setup_kernel(
    const int* an, const float* pos, const float* emb,
    const float* msg_w1, const float* msg_b1, const float* msg_w2,
    const float* msg_b2, const float* upd_w1,
    const float* centers, const float* widths, float* ws)
{
  __shared__ float xl[2][128];
  const int vb = blockIdx.x, tid = threadIdx.x;
  float* x    = ws + WS_X;
  float* t    = ws + WS_T;
  float* Wc   = ws + WS_WC;
  float* bc   = ws + WS_BC;
  float* corr = ws + WS_CORR;
  float* pool = ws + WS_POOL;
  const int lane = tid & 63;
  const int quad = lane >> 4, l16 = lane & 15;

  if (vb < 256) {
    const int jj = tid >> 7, h = tid & 127;
    const int i = vb * 2 + jj;
    int a = an[i]; a = a < 0 ? 0 : (a > 99 ? 99 : a);
    float xv = emb[a * 128 + h];
    x[i * 128 + h] = xv;
    xl[jj][h] = xv;
    __syncthreads();
    float a0 = 0.0f, a1 = 0.0f;
    for (int k = 0; k < 128; k += 2) {
      a0 += xl[jj][k] * msg_w1[k * 128 + h];
      a1 += xl[jj][k + 1] * msg_w1[(k + 1) * 128 + h];
    }
    t[i * 128 + h] = msg_b1[h] + a0 + a1;
  } else if (vb < 768) {
    const int j = vb - 256;
    const int g = tid >> 6;
    const float pjx = pos[j * 3], pjy = pos[j * 3 + 1], pjz = pos[j * 3 + 2];
    float cr[8], k2[8];
#pragma unroll
    for (int u = 0; u < 8; ++u) {
      int r = quad * 8 + u;
      float w = widths[r];
      cr[u] = centers[r];
      k2[u] = -0.7213475204444817f / (w * w);
    }
    short8* AFp = (short8*)(ws + WS_AF);
    for (int iter = 0; iter < 8; ++iter) {
      int ic = iter * 4 + g;
      int i = ic * 16 + l16;
      float dx = pos[i * 3] - pjx, dy = pos[i * 3 + 1] - pjy, dz = pos[i * 3 + 2] - pjz;
      float d = sqrtf(dx * dx + dy * dy + dz * dz);
      short8 v;
#pragma unroll
      for (int u = 0; u < 8; ++u) {
        float dd = d - cr[u];
        v[u] = f2bf(fexp2(dd * dd * k2[u]));
      }
      AFp[(j * 32 + ic) * 64 + lane] = v;
    }
  } else if (vb < 832) {
    const int idx = vb - 768;
    const int b = idx >> 4, rg = idx & 15;
    const int jj = tid >> 7, h = tid & 127;
    const float* uw1b = upd_w1 + b * 32768 + 16384;
    for (int p = 0; p < 4; ++p) {
      int k = rg * 8 + p * 2 + jj;
      const float* mw2 = msg_w2 + b * 16384 + k * 128;
      float a0 = 0.0f, a1 = 0.0f;
      for (int m = 0; m < 128; m += 2) {
        a0 += mw2[m] * uw1b[m * 128 + h];
        a1 += mw2[m + 1] * uw1b[(m + 1) * 128 + h];
      }
      Wc[b * 16384 + k * 128 + h] = a0 + a1;
    }
  } else if (vb < 836) {
    const int b = vb - 832;
    if (tid < 128) {
      const float* mb2 = msg_b2 + b * 128;
      const float* uw1b = upd_w1 + b * 32768 + 16384;
      float a0 = 0.0f, a1 = 0.0f;
      for (int m = 0; m < 128; m += 2) {
        a0 += mb2[m] * uw1b[m * 128 + tid];
        a1 += mb2[m + 1] * uw1b[(m + 1) * 128 + tid];
      }
      bc[b * 128 + tid] = a0 + a1;
    }
  } else if (vb < 840) {
    const int b = vb - 836;
    const float* w1rb = msg_w1 + b * 188 * 128 + 16384;
    short8* dst = (short8*)(ws + WS_BF) + b * 512;
    for (int slot = tid; slot < 512; slot += 256) {
      int ln = slot & 63, ht = slot >> 6;
      int qd = ln >> 4, l = ln & 15;
      short8 v;
#pragma unroll
      for (int u = 0; u < 8; ++u) {
        int r = qd * 8 + u;
        v[u] = f2bf(w1rb[r * 128 + ht * 16 + l]);
      }
      dst[slot] = v;
    }
  } else if (vb < 844) {
    const int b = vb - 840;
    if (tid < 128) {
      const float* w1rb = msg_w1 + b * 188 * 128 + 16384;
      float acc = 0.0f;
      for (int r = 0; r < KTRUNC; ++r) {
        float c = centers[r], w = widths[r];
        float rb = fexp2(c * c * (-0.7213475204444817f / (w * w)));
        acc += bf2f(f2bf(rb)) * bf2f(f2bf(w1rb[r * 128 + tid]));
      }
      corr[b * 128 + tid] = acc;
    }
  } else {
    for (int idx = tid; idx < 2048; idx += 256) pool[idx] = 0.0f;
  }
}

// ---------------------------------------------------------------------------
// msg: 2048 blocks per layer; R4-proven INLINE body (jj-outer form).
// ---------------------------------------------------------------------------
__global__ __launch_bounds__(256) void msg_kernel(
    const short8* AFp, const short8* BFb, const float* t, float* part)
{
  const int vb = blockIdx.x, tid = threadIdx.x;
  const int lane = tid & 63, wv = tid >> 6;
  const int quad = lane >> 4, l16 = lane & 15;
  const int jt = vb & 31, is = (vb >> 5) & 31, hh = vb >> 10;
  const int i0 = is * 16;
  short8 AFv[4];
#pragma unroll
  for (int jj = 0; jj < 4; ++jj) {
    const int j = jt * 16 + wv * 4 + jj;
    AFv[jj] = AFp[(j * 32 + is) * 64 + lane];
  }
  short8 Bf[4];
#pragma unroll
  for (int htl = 0; htl < 4; ++htl)
    Bf[htl] = BFb[(hh * 4 + htl) * 64 + lane];
  f32x4 Ct[4];
#pragma unroll
  for (int htl = 0; htl < 4; ++htl)
#pragma unroll
    for (int r = 0; r < 4; ++r)
      Ct[htl][r] = t[(i0 + quad * 4 + r) * 128 + (hh * 4 + htl) * 16 + l16];
#pragma unroll
  for (int jj = 0; jj < 4; ++jj) {
    const int j = jt * 16 + wv * 4 + jj;
    float acc[4];
#pragma unroll
    for (int htl = 0; htl < 4; ++htl) {
      f32x4 C = Ct[htl];
      C = __builtin_amdgcn_mfma_f32_16x16x32_bf16(AFv[jj], Bf[htl], C, 0, 0, 0);
      float a = 0.0f;
#pragma unroll
      for (int r = 0; r < 4; ++r) {
        float z = C[r];
        float e = fexp2(z * -1.44269504f);
        a += z * frcp(1.0f + e);
      }
      acc[htl] = a;
    }
    float* prow = part + (is * 512 + j) * 128 + hh * 64;
#pragma unroll
    for (int htl = 0; htl < 4; ++htl) {
      float a = acc[htl];
      a += __shfl_down(a, 32, 64);
      a += __shfl_down(a, 16, 64);
      if (lane < 16) prow[htl * 16 + l16] = a;
    }
  }
}

// ---------------------------------------------------------------------------
// update: one atom per block (512 blocks), 2 k-halves x 128 h.
// For b==3: after the pool atomicAdd, a done-counter in the poisoned bar
// region elects the LAST block to run the final MLP inline (replaces the
// separate 1-block final_kernel; same fence+counter pattern validated in
// the fused kernel R4-R15).
// ---------------------------------------------------------------------------
__global__ __launch_bounds__(256) void update_kernel(
    float* ws, const int* batch, int b,
    const float* msg_w1, const float* msg_b1,
    const float* upd_w1, const float* upd_b1,
    const float* upd_w2, const float* upd_b2,
    const float* ow1, const float* ob1, const float* ow2, const float* ob2,
    float* out)
{
  union Sm {
    struct { float xs[128], as[128], vs[128], ps[2][128]; } u;
    struct { float pooled[16][128]; float h1[16][64]; int cnti[16]; } f;
  };
  __shared__ Sm sm;
  __shared__ unsigned lastflag;
  const int j = blockIdx.x, tid = threadIdx.x;
  float* x    = ws + WS_X;
  float* t    = ws + WS_T;
  float* pool = ws + WS_POOL;
  const float* part = ws + WS_PART;
  const float* uw1 = upd_w1 + b * 32768;
  const float* ub1 = upd_b1 + b * 128;
  const float* uw2 = upd_w2 + b * 16384;
  const float* ub2 = upd_b2 + b * 128;
  const float* Wcb = ws + WS_WC + b * 16384;
  const float* bcb = ws + WS_BC + b * 128;
  const float* corb = ws + WS_CORR + b * 128;
  const int h = tid & 127, kh = tid >> 7;
  const int k0 = kh * 64;

  if (kh == 0) sm.u.xs[h] = x[j * 128 + h];
  float p0 = 0.0f, p1 = 0.0f;
#pragma unroll
  for (int is = kh * 16; is < kh * 16 + 16; is += 2) {
    p0 += part[(is * 512 + j) * 128 + h];
    p1 += part[((is + 1) * 512 + j) * 128 + h];
  }
  sm.u.ps[kh][h] = p0 + p1;
  __syncthreads();
  if (kh == 0) {
    float tcur = t[j * 128 + h];
    sm.u.as[h] = sm.u.ps[0][h] + sm.u.ps[1][h] - silu_f(tcur + corb[h]);
  }
  __syncthreads();
  float a0 = 0.0f, a1 = 0.0f;
  for (int k = k0; k < k0 + 64; k += 2) {
    a0 += sm.u.xs[k] * uw1[k * 128 + h] + sm.u.as[k] * Wcb[k * 128 + h];
    a1 += sm.u.xs[k + 1] * uw1[(k + 1) * 128 + h] + sm.u.as[k + 1] * Wcb[(k + 1) * 128 + h];
  }
  sm.u.ps[kh][h] = a0 + a1;
  __syncthreads();
  if (kh == 0)
    sm.u.vs[h] = silu_f(511.0f * bcb[h] + ub1[h] + sm.u.ps[0][h] + sm.u.ps[1][h]);
  __syncthreads();
  float c0 = 0.0f, c1 = 0.0f;
  for (int k = k0; k < k0 + 64; k += 2) {
    c0 += sm.u.vs[k] * uw2[k * 128 + h];
    c1 += sm.u.vs[k + 1] * uw2[(k + 1) * 128 + h];
  }
  sm.u.ps[kh][h] = c0 + c1;
  __syncthreads();
  float xn_loc = 0.0f;
  if (kh == 0) {
    xn_loc = sm.u.xs[h] + ub2[h] + sm.u.ps[0][h] + sm.u.ps[1][h];
    x[j * 128 + h] = xn_loc;
    sm.u.xs[h] = xn_loc;
  }
  __syncthreads();
  if (b < 3) {
    const float* w1x_next = msg_w1 + (b + 1) * 188 * 128;
    const float* b1_next = msg_b1 + (b + 1) * 128;
    float t0 = 0.0f, t1 = 0.0f;
    for (int k = k0; k < k0 + 64; k += 2) {
      t0 += sm.u.xs[k] * w1x_next[k * 128 + h];
      t1 += sm.u.xs[k + 1] * w1x_next[(k + 1) * 128 + h];
    }
    sm.u.ps[kh][h] = t0 + t1;
    __syncthreads();
    if (kh == 0) t[j * 128 + h] = b1_next[h] + sm.u.ps[0][h] + sm.u.ps[1][h];
    return;
  }

  // ---- b == 3: pool accumulate, then last-done block runs the final MLP ----
  if (kh == 0) atomicAdd(pool + batch[j] * 128 + h, sm.u.xs[h]);
  __syncthreads();
  unsigned* bar = (unsigned*)(ws + WS_BAR);
  if (tid == 0) {
    __threadfence();  // make this block's pool adds visible before counting
    unsigned old = atomicAdd(&bar[248], 1u);
    lastflag = (old - 0xAAAAAAAAu == (unsigned)gridDim.x - 1) ? 1u : 0u;
  }
  __syncthreads();
  if (!lastflag) return;
  __threadfence();  // acquire: all 512 blocks' pool adds visible

  if (tid < 16) sm.f.cnti[tid] = 0;
  __syncthreads();
  atomicAdd(&sm.f.cnti[batch[tid]], 1);
  atomicAdd(&sm.f.cnti[batch[tid + 256]], 1);
  __syncthreads();
  for (int idx = tid; idx < 2048; idx += 256) {
    int m = idx >> 7;
    float c = sm.f.cnti[m] > 0 ? (float)sm.f.cnti[m] : 1.0f;
    ((float*)sm.f.pooled)[idx] = pool[idx] / c;
  }
  __syncthreads();
  for (int idx = tid; idx < 1024; idx += 256) {
    int m = idx >> 6, o = idx & 63;
    float a0f = 0.0f, a1f = 0.0f;
    for (int k = 0; k < 128; k += 2) {
      a0f += sm.f.pooled[m][k] * ow1[k * 64 + o];
      a1f += sm.f.pooled[m][k + 1] * ow1[(k + 1) * 64 + o];
    }
    sm.f.h1[m][o] = silu_f(ob1[o] + a0f + a1f);
  }
  __syncthreads();
  if (tid < 16) {
    float acc = ob2[0];
    for (int o = 0; o < 64; ++o) acc += sm.f.h1[tid][o] * ow2[o];
    out[tid] = acc;
  }
}

// ===========================================================================
// kernel_launch: pure split dispatch, 9 launches, no host API beyond
// launches -> unconditionally graph-capture-safe. No probes.
// ===========================================================================
extern "C" void kernel_launch(void* const* d_in, const int* in_sizes, int n_in,
                              void* d_out, int out_size, void* d_ws, size_t ws_size,
                              hipStream_t stream) {
  const int*   an      = (const int*)d_in[0];
  const float* pos     = (const float*)d_in[1];
  const int*   batch   = (const int*)d_in[2];
  const float* emb     = (const float*)d_in[3];
  const float* centers = (const float*)d_in[4];
  const float* widths  = (const float*)d_in[5];
  const float* msg_w1  = (const float*)d_in[6];
  const float* msg_b1  = (const float*)d_in[7];
  const float* msg_w2  = (const float*)d_in[8];
  const float* msg_b2  = (const float*)d_in[9];
  const float* upd_w1  = (const float*)d_in[10];
  const float* upd_b1  = (const float*)d_in[11];
  const float* upd_w2  = (const float*)d_in[12];
  const float* upd_b2  = (const float*)d_in[13];
  const float* ow1     = (const float*)d_in[14];
  const float* ob1     = (const float*)d_in[15];
  const float* ow2     = (const float*)d_in[16];
  const float* ob2     = (const float*)d_in[17];
  float* ws  = (float*)d_ws;
  float* out = (float*)d_out;

  const short8* AFp = (const short8*)(ws + WS_AF);
  const short8* BFp = (const short8*)(ws + WS_BF);

  setup_kernel<<<dim3(845), dim3(256), 0, stream>>>(
      an, pos, emb, msg_w1, msg_b1, msg_w2, msg_b2, upd_w1, centers, widths, ws);
  for (int b = 0; b < 4; ++b) {
    msg_kernel<<<dim3(2048), dim3(256), 0, stream>>>(
        AFp, BFp + b * 512, ws + WS_T, ws + WS_PART);
    update_kernel<<<dim3(512), dim3(256), 0, stream>>>(
        ws, batch, b, msg_w1, msg_b1, upd_w1, upd_b1, upd_w2, upd_b2,
        ow1, ob1, ow2, ob2, out);
  }
}

// Round 18
// 203.359 us; speedup vs baseline: 3.2506x; 1.0631x over previous
//
#include <hip/hip_runtime.h>
#include <hip/hip_bf16.h>

#define NRBF 60
#define KTRUNC 32          // rbf r>=32 is < 1.4e-13 for d <= sqrt(3) < cutoff

// ws float offsets
#define WS_X      0          // 512*128
#define WS_T      65536      // 512*128
#define WS_WC     131072     // 4*128*128
#define WS_BC     196608     // 4*128
#define WS_CORR   197120     // 4*128
#define WS_POOL   197632     // 16*128
#define WS_BAR    199680     // (unused this round; kept for layout stability)
#define WS_BF     199936     // 4 layers * 512 short8 (8192 floats)
#define WS_PART   208128     // 32*512*128 partials (2097152 floats)
#define WS_AF     2305280    // 512*32*64 short8 (4194304 floats) = 16.8 MB
#define WS_TOTALF 6499584    // floats

typedef short short8 __attribute__((ext_vector_type(8)));
typedef float f32x4 __attribute__((ext_vector_type(4)));

__device__ inline float fexp2(float x) { return __builtin_amdgcn_exp2f(x); }
__device__ inline float frcp(float x) { return __builtin_amdgcn_rcpf(x); }
__device__ inline float silu_f(float z) {
  float e = fexp2(z * -1.44269504f);
  return z * frcp(1.0f + e);
}
__device__ inline short f2bf(float f) {
  unsigned u = __float_as_uint(f);
  unsigned r = (u + 0x7FFFu + ((u >> 16) & 1u)) >> 16;
  return (short)r;
}
__device__ inline float bf2f(short b) {
  unsigned u = ((unsigned)(unsigned short)b) << 16;
  return __uint_as_float(u);
}

// ===========================================================================
// Ledger (timed): split 10-dispatch = 206us (BEST) | fused inline nb=1 = 207
// | merged-final 9-dispatch = 216 (R17: union-LDS/code bloat taxed all 4
// update dispatches; dispatch boundaries are ~free) | fused noinline = 521
// | fused nb=2 = 651-687. This round: exact baseline revert + ONE isolated
// lever: final_kernel parallelized 1 block -> 16 blocks (one per molecule).
// ===========================================================================

// ---------------------------------------------------------------------------
// setup: one vblock per block (845 blocks). R7-session-proven shapes.
// ---------------------------------------------------------------------------
__global__ __launch_bounds__(256) void setup_kernel(
    const int* an, const float* pos, const float* emb,
    const float* msg_w1, const float* msg_b1, const float* msg_w2,
    const float* msg_b2, const float* upd_w1,
    const float* centers, const float* widths, float* ws)
{
  __shared__ float xl[2][128];
  const int vb = blockIdx.x, tid = threadIdx.x;
  float* x    = ws + WS_X;
  float* t    = ws + WS_T;
  float* Wc   = ws + WS_WC;
  float* bc   = ws + WS_BC;
  float* corr = ws + WS_CORR;
  float* pool = ws + WS_POOL;
  const int lane = tid & 63;
  const int quad = lane >> 4, l16 = lane & 15;

  if (vb < 256) {
    const int jj = tid >> 7, h = tid & 127;
    const int i = vb * 2 + jj;
    int a = an[i]; a = a < 0 ? 0 : (a > 99 ? 99 : a);
    float xv = emb[a * 128 + h];
    x[i * 128 + h] = xv;
    xl[jj][h] = xv;
    __syncthreads();
    float a0 = 0.0f, a1 = 0.0f;
    for (int k = 0; k < 128; k += 2) {
      a0 += xl[jj][k] * msg_w1[k * 128 + h];
      a1 += xl[jj][k + 1] * msg_w1[(k + 1) * 128 + h];
    }
    t[i * 128 + h] = msg_b1[h] + a0 + a1;
  } else if (vb < 768) {
    const int j = vb - 256;
    const int g = tid >> 6;
    const float pjx = pos[j * 3], pjy = pos[j * 3 + 1], pjz = pos[j * 3 + 2];
    float cr[8], k2[8];
#pragma unroll
    for (int u = 0; u < 8; ++u) {
      int r = quad * 8 + u;
      float w = widths[r];
      cr[u] = centers[r];
      k2[u] = -0.7213475204444817f / (w * w);
    }
    short8* AFp = (short8*)(ws + WS_AF);
    for (int iter = 0; iter < 8; ++iter) {
      int ic = iter * 4 + g;
      int i = ic * 16 + l16;
      float dx = pos[i * 3] - pjx, dy = pos[i * 3 + 1] - pjy, dz = pos[i * 3 + 2] - pjz;
      float d = sqrtf(dx * dx + dy * dy + dz * dz);
      short8 v;
#pragma unroll
      for (int u = 0; u < 8; ++u) {
        float dd = d - cr[u];
        v[u] = f2bf(fexp2(dd * dd * k2[u]));
      }
      AFp[(j * 32 + ic) * 64 + lane] = v;
    }
  } else if (vb < 832) {
    const int idx = vb - 768;
    const int b = idx >> 4, rg = idx & 15;
    const int jj = tid >> 7, h = tid & 127;
    const float* uw1b = upd_w1 + b * 32768 + 16384;
    for (int p = 0; p < 4; ++p) {
      int k = rg * 8 + p * 2 + jj;
      const float* mw2 = msg_w2 + b * 16384 + k * 128;
      float a0 = 0.0f, a1 = 0.0f;
      for (int m = 0; m < 128; m += 2) {
        a0 += mw2[m] * uw1b[m * 128 + h];
        a1 += mw2[m + 1] * uw1b[(m + 1) * 128 + h];
      }
      Wc[b * 16384 + k * 128 + h] = a0 + a1;
    }
  } else if (vb < 836) {
    const int b = vb - 832;
    if (tid < 128) {
      const float* mb2 = msg_b2 + b * 128;
      const float* uw1b = upd_w1 + b * 32768 + 16384;
      float a0 = 0.0f, a1 = 0.0f;
      for (int m = 0; m < 128; m += 2) {
        a0 += mb2[m] * uw1b[m * 128 + tid];
        a1 += mb2[m + 1] * uw1b[(m + 1) * 128 + tid];
      }
      bc[b * 128 + tid] = a0 + a1;
    }
  } else if (vb < 840) {
    const int b = vb - 836;
    const float* w1rb = msg_w1 + b * 188 * 128 + 16384;
    short8* dst = (short8*)(ws + WS_BF) + b * 512;
    for (int slot = tid; slot < 512; slot += 256) {
      int ln = slot & 63, ht = slot >> 6;
      int qd = ln >> 4, l = ln & 15;
      short8 v;
#pragma unroll
      for (int u = 0; u < 8; ++u) {
        int r = qd * 8 + u;
        v[u] = f2bf(w1rb[r * 128 + ht * 16 + l]);
      }
      dst[slot] = v;
    }
  } else if (vb < 844) {
    const int b = vb - 840;
    if (tid < 128) {
      const float* w1rb = msg_w1 + b * 188 * 128 + 16384;
      float acc = 0.0f;
      for (int r = 0; r < KTRUNC; ++r) {
        float c = centers[r], w = widths[r];
        float rb = fexp2(c * c * (-0.7213475204444817f / (w * w)));
        acc += bf2f(f2bf(rb)) * bf2f(f2bf(w1rb[r * 128 + tid]));
      }
      corr[b * 128 + tid] = acc;
    }
  } else {
    for (int idx = tid; idx < 2048; idx += 256) pool[idx] = 0.0f;
  }
}

// ---------------------------------------------------------------------------
// msg: 2048 blocks per layer; R4-proven INLINE body (jj-outer form).
// ---------------------------------------------------------------------------
__global__ __launch_bounds__(256) void msg_kernel(
    const short8* AFp, const short8* BFb, const float* t, float* part)
{
  const int vb = blockIdx.x, tid = threadIdx.x;
  const int lane = tid & 63, wv = tid >> 6;
  const int quad = lane >> 4, l16 = lane & 15;
  const int jt = vb & 31, is = (vb >> 5) & 31, hh = vb >> 10;
  const int i0 = is * 16;
  short8 AFv[4];
#pragma unroll
  for (int jj = 0; jj < 4; ++jj) {
    const int j = jt * 16 + wv * 4 + jj;
    AFv[jj] = AFp[(j * 32 + is) * 64 + lane];
  }
  short8 Bf[4];
#pragma unroll
  for (int htl = 0; htl < 4; ++htl)
    Bf[htl] = BFb[(hh * 4 + htl) * 64 + lane];
  f32x4 Ct[4];
#pragma unroll
  for (int htl = 0; htl < 4; ++htl)
#pragma unroll
    for (int r = 0; r < 4; ++r)
      Ct[htl][r] = t[(i0 + quad * 4 + r) * 128 + (hh * 4 + htl) * 16 + l16];
#pragma unroll
  for (int jj = 0; jj < 4; ++jj) {
    const int j = jt * 16 + wv * 4 + jj;
    float acc[4];
#pragma unroll
    for (int htl = 0; htl < 4; ++htl) {
      f32x4 C = Ct[htl];
      C = __builtin_amdgcn_mfma_f32_16x16x32_bf16(AFv[jj], Bf[htl], C, 0, 0, 0);
      float a = 0.0f;
#pragma unroll
      for (int r = 0; r < 4; ++r) {
        float z = C[r];
        float e = fexp2(z * -1.44269504f);
        a += z * frcp(1.0f + e);
      }
      acc[htl] = a;
    }
    float* prow = part + (is * 512 + j) * 128 + hh * 64;
#pragma unroll
    for (int htl = 0; htl < 4; ++htl) {
      float a = acc[htl];
      a += __shfl_down(a, 32, 64);
      a += __shfl_down(a, 16, 64);
      if (lane < 16) prow[htl * 16 + l16] = a;
    }
  }
}

// ---------------------------------------------------------------------------
// update: one atom per block (512 blocks), 2 k-halves x 128 h — the exact
// 206us-baseline body (pool atomicAdd at b==3; no done-counter, no final).
// ---------------------------------------------------------------------------
__global__ __launch_bounds__(256) void update_kernel(
    float* ws, const int* batch, int b,
    const float* msg_w1, const float* msg_b1,
    const float* upd_w1, const float* upd_b1,
    const float* upd_w2, const float* upd_b2)
{
  __shared__ float xs[128], as[128], vs[128], ps[2][128];
  const int j = blockIdx.x, tid = threadIdx.x;
  float* x    = ws + WS_X;
  float* t    = ws + WS_T;
  float* pool = ws + WS_POOL;
  const float* part = ws + WS_PART;
  const float* uw1 = upd_w1 + b * 32768;
  const float* ub1 = upd_b1 + b * 128;
  const float* uw2 = upd_w2 + b * 16384;
  const float* ub2 = upd_b2 + b * 128;
  const float* Wcb = ws + WS_WC + b * 16384;
  const float* bcb = ws + WS_BC + b * 128;
  const float* corb = ws + WS_CORR + b * 128;
  const int h = tid & 127, kh = tid >> 7;
  const int k0 = kh * 64;

  if (kh == 0) xs[h] = x[j * 128 + h];
  float p0 = 0.0f, p1 = 0.0f;
#pragma unroll
  for (int is = kh * 16; is < kh * 16 + 16; is += 2) {
    p0 += part[(is * 512 + j) * 128 + h];
    p1 += part[((is + 1) * 512 + j) * 128 + h];
  }
  ps[kh][h] = p0 + p1;
  __syncthreads();
  if (kh == 0) {
    float tcur = t[j * 128 + h];
    as[h] = ps[0][h] + ps[1][h] - silu_f(tcur + corb[h]);
  }
  __syncthreads();
  float a0 = 0.0f, a1 = 0.0f;
  for (int k = k0; k < k0 + 64; k += 2) {
    a0 += xs[k] * uw1[k * 128 + h] + as[k] * Wcb[k * 128 + h];
    a1 += xs[k + 1] * uw1[(k + 1) * 128 + h] + as[k + 1] * Wcb[(k + 1) * 128 + h];
  }
  ps[kh][h] = a0 + a1;
  __syncthreads();
  if (kh == 0)
    vs[h] = silu_f(511.0f * bcb[h] + ub1[h] + ps[0][h] + ps[1][h]);
  __syncthreads();
  float c0 = 0.0f, c1 = 0.0f;
  for (int k = k0; k < k0 + 64; k += 2) {
    c0 += vs[k] * uw2[k * 128 + h];
    c1 += vs[k + 1] * uw2[(k + 1) * 128 + h];
  }
  ps[kh][h] = c0 + c1;
  __syncthreads();
  if (kh == 0) {
    float xn = xs[h] + ub2[h] + ps[0][h] + ps[1][h];
    x[j * 128 + h] = xn;
    xs[h] = xn;
  }
  __syncthreads();
  if (b < 3) {
    const float* w1x_next = msg_w1 + (b + 1) * 188 * 128;
    const float* b1_next = msg_b1 + (b + 1) * 128;
    float t0 = 0.0f, t1 = 0.0f;
    for (int k = k0; k < k0 + 64; k += 2) {
      t0 += xs[k] * w1x_next[k * 128 + h];
      t1 += xs[k + 1] * w1x_next[(k + 1) * 128 + h];
    }
    ps[kh][h] = t0 + t1;
    __syncthreads();
    if (kh == 0) t[j * 128 + h] = b1_next[h] + ps[0][h] + ps[1][h];
    __syncthreads();
  } else {
    if (kh == 0) atomicAdd(pool + batch[j] * 128 + h, xs[h]);
    __syncthreads();
  }
}

// ---------------------------------------------------------------------------
// final: 16 blocks (one per molecule) — this round's single lever. Each
// block counts its molecule's atoms, normalizes the pool row, and runs the
// 128->64->1 MLP for its own output. Work per block drops 16x vs the
// 1-block baseline; all blocks run concurrently.
// ---------------------------------------------------------------------------
__global__ __launch_bounds__(256) void final_kernel(
    const float* pool, const int* batch,
    const float* ow1, const float* ob1,
    const float* ow2, const float* ob2, float* out)
{
  __shared__ float pooled[128];
  __shared__ float h1[64];
  __shared__ int cnt;
  const int m = blockIdx.x, tid = threadIdx.x;
  if (tid == 0) cnt = 0;
  __syncthreads();
  int c0 = (batch[tid] == m ? 1 : 0) + (batch[tid + 256] == m ? 1 : 0);
  if (c0) atomicAdd(&cnt, c0);
  __syncthreads();
  float c = cnt > 0 ? (float)cnt : 1.0f;
  if (tid < 128) pooled[tid] = pool[m * 128 + tid] / c;
  __syncthreads();
  if (tid < 64) {
    float a0 = 0.0f, a1 = 0.0f;
    for (int k = 0; k < 128; k += 2) {
      a0 += pooled[k] * ow1[k * 64 + tid];
      a1 += pooled[k + 1] * ow1[(k + 1) * 64 + tid];
    }
    h1[tid] = silu_f(ob1[tid] + a0 + a1);
  }
  __syncthreads();
  if (tid == 0) {
    float acc = ob2[0];
    for (int o = 0; o < 64; ++o) acc += h1[o] * ow2[o];
    out[m] = acc;
  }
}

// ===========================================================================
// kernel_launch: pure split dispatch, 10 launches (baseline structure),
// graph-capture-safe, no probes.
// ===========================================================================
extern "C" void kernel_launch(void* const* d_in, const int* in_sizes, int n_in,
                              void* d_out, int out_size, void* d_ws, size_t ws_size,
                              hipStream_t stream) {
  const int*   an      = (const int*)d_in[0];
  const float* pos     = (const float*)d_in[1];
  const int*   batch   = (const int*)d_in[2];
  const float* emb     = (const float*)d_in[3];
  const float* centers = (const float*)d_in[4];
  const float* widths  = (const float*)d_in[5];
  const float* msg_w1  = (const float*)d_in[6];
  const float* msg_b1  = (const float*)d_in[7];
  const float* msg_w2  = (const float*)d_in[8];
  const float* msg_b2  = (const float*)d_in[9];
  const float* upd_w1  = (const float*)d_in[10];
  const float* upd_b1  = (const float*)d_in[11];
  const float* upd_w2  = (const float*)d_in[12];
  const float* upd_b2  = (const float*)d_in[13];
  const float* ow1     = (const float*)d_in[14];
  const float* ob1     = (const float*)d_in[15];
  const float* ow2     = (const float*)d_in[16];
  const float* ob2     = (const float*)d_in[17];
  float* ws  = (float*)d_ws;
  float* out = (float*)d_out;

  const short8* AFp = (const short8*)(ws + WS_AF);
  const short8* BFp = (const short8*)(ws + WS_BF);

  setup_kernel<<<dim3(845), dim3(256), 0, stream>>>(
      an, pos, emb, msg_w1, msg_b1, msg_w2, msg_b2, upd_w1, centers, widths, ws);
  for (int b = 0; b < 4; ++b) {
    msg_kernel<<<dim3(2048), dim3(256), 0, stream>>>(
        AFp, BFp + b * 512, ws + WS_T, ws + WS_PART);
    update_kernel<<<dim3(512), dim3(256), 0, stream>>>(
        ws, batch, b, msg_w1, msg_b1, upd_w1, upd_b1, upd_w2, upd_b2);
  }
  final_kernel<<<dim3(16), dim3(256), 0, stream>>>(
      ws + WS_POOL, batch, ow1, ob1, ow2, ob2, out);
}